// Round 2
// baseline (207.937 us; speedup 1.0000x reference)
//
#include <hip/hip_runtime.h>

#define LOG_CLAMP -100.0f
#define LN2 0.69314718055994530942f

// ws layout: ws[0] = S1 (sum over gt==1 of -max(log x, -100))
//            ws[1] = S0 (sum over gt==0 of -max(log1p(-x), -100))
//            ws[2] = s  (count of gt==1)

__device__ __forceinline__ float fast_ln(float v) {
  // v_log_f32 = log2(v); scale to natural log. log2(0) = -inf -> clamped by caller.
  return __builtin_amdgcn_logf(v) * LN2;
}

__global__ __launch_bounds__(256) void bce_reduce_kernel(
    const float* __restrict__ x, const int* __restrict__ gt,
    int n, double* __restrict__ ws) {
  float s1 = 0.0f, s0 = 0.0f, cnt = 0.0f;

  const int tid = blockIdx.x * blockDim.x + threadIdx.x;
  const int stride = gridDim.x * blockDim.x;

  const int n4 = n >> 2;
  const float4* __restrict__ x4 = reinterpret_cast<const float4*>(x);
  const int4* __restrict__ g4 = reinterpret_cast<const int4*>(gt);

  for (int i = tid; i < n4; i += stride) {
    float4 xv = x4[i];
    int4 gv = g4[i];

    // Branchless: pick the log argument per element, single native log.
    {
      float t = gv.x ? xv.x : 1.0f - xv.x;
      float l = fmaxf(fast_ln(t), LOG_CLAMP);
      s1 -= gv.x ? l : 0.0f;
      s0 -= gv.x ? 0.0f : l;
      cnt += gv.x ? 1.0f : 0.0f;
    }
    {
      float t = gv.y ? xv.y : 1.0f - xv.y;
      float l = fmaxf(fast_ln(t), LOG_CLAMP);
      s1 -= gv.y ? l : 0.0f;
      s0 -= gv.y ? 0.0f : l;
      cnt += gv.y ? 1.0f : 0.0f;
    }
    {
      float t = gv.z ? xv.z : 1.0f - xv.z;
      float l = fmaxf(fast_ln(t), LOG_CLAMP);
      s1 -= gv.z ? l : 0.0f;
      s0 -= gv.z ? 0.0f : l;
      cnt += gv.z ? 1.0f : 0.0f;
    }
    {
      float t = gv.w ? xv.w : 1.0f - xv.w;
      float l = fmaxf(fast_ln(t), LOG_CLAMP);
      s1 -= gv.w ? l : 0.0f;
      s0 -= gv.w ? 0.0f : l;
      cnt += gv.w ? 1.0f : 0.0f;
    }
  }

  // tail (n not divisible by 4)
  for (int i = (n4 << 2) + tid; i < n; i += stride) {
    float xv = x[i];
    int gv = gt[i];
    float t = gv ? xv : 1.0f - xv;
    float l = fmaxf(fast_ln(t), LOG_CLAMP);
    s1 -= gv ? l : 0.0f;
    s0 -= gv ? 0.0f : l;
    cnt += gv ? 1.0f : 0.0f;
  }

  // wave-level reduction (64 lanes)
  for (int off = 32; off > 0; off >>= 1) {
    s1  += __shfl_down(s1, off, 64);
    s0  += __shfl_down(s0, off, 64);
    cnt += __shfl_down(cnt, off, 64);
  }

  // cross-wave reduction via LDS (256 threads = 4 waves)
  __shared__ float red[3][4];
  const int lane = threadIdx.x & 63;
  const int wave = threadIdx.x >> 6;
  if (lane == 0) {
    red[0][wave] = s1;
    red[1][wave] = s0;
    red[2][wave] = cnt;
  }
  __syncthreads();
  if (threadIdx.x == 0) {
    float bs1 = red[0][0] + red[0][1] + red[0][2] + red[0][3];
    float bs0 = red[1][0] + red[1][1] + red[1][2] + red[1][3];
    float bc  = red[2][0] + red[2][1] + red[2][2] + red[2][3];
    atomicAdd(&ws[0], (double)bs1);
    atomicAdd(&ws[1], (double)bs0);
    atomicAdd(&ws[2], (double)bc);
  }
}

__global__ void bce_finalize_kernel(const double* __restrict__ ws,
                                    float* __restrict__ out, double n) {
  double S1 = ws[0];
  double S0 = ws[1];
  double s  = ws[2];
  // result = S1/(2s) + S0/(2(n-s))
  double res = S1 / (2.0 * s) + S0 / (2.0 * (n - s));
  out[0] = (float)res;
}

extern "C" void kernel_launch(void* const* d_in, const int* in_sizes, int n_in,
                              void* d_out, int out_size, void* d_ws, size_t ws_size,
                              hipStream_t stream) {
  const float* x = (const float*)d_in[0];
  const int* gt = (const int*)d_in[1];
  float* out = (float*)d_out;
  int n = in_sizes[0];

  double* ws = (double*)d_ws;
  // d_ws is re-poisoned to 0xAA before every launch — zero our accumulators.
  hipMemsetAsync(ws, 0, 3 * sizeof(double), stream);

  const int block = 256;
  const int grid = 2048;  // 256 CUs x 8 blocks/CU; grid-stride covers the rest
  bce_reduce_kernel<<<grid, block, 0, stream>>>(x, gt, n, ws);
  bce_finalize_kernel<<<1, 1, 0, stream>>>(ws, out, (double)n);
}

// Round 3
// 148.563 us; speedup vs baseline: 1.3997x; 1.3997x over previous
//
#include <hip/hip_runtime.h>

#define LOG_CLAMP -100.0f
#define LN2 0.69314718055994530942f
#define GRID 2048
#define BLOCK 256

// Stage 1: per-block partials, NO atomics (deterministic, no same-line contention).
// ws layout (float): part_s1[GRID] | part_s0[GRID] | part_cnt[GRID]
// Stage 2: one block reduces the partials in double and writes the scalar.

__device__ __forceinline__ float fast_ln(float v) {
  // v_log_f32 = log2(v); log2(0) = -inf -> fmax clamp handles it.
  return __builtin_amdgcn_logf(v) * LN2;
}

#define ACC1(xe, ge)                                  \
  {                                                   \
    float t = (ge) ? (xe) : 1.0f - (xe);              \
    float l = fmaxf(fast_ln(t), LOG_CLAMP);           \
    s1 -= (ge) ? l : 0.0f;                            \
    s0 -= (ge) ? 0.0f : l;                            \
    cnt += (ge) ? 1.0f : 0.0f;                        \
  }

#define ACC4(xv, gv)                                  \
  ACC1(xv.x, gv.x) ACC1(xv.y, gv.y)                   \
  ACC1(xv.z, gv.z) ACC1(xv.w, gv.w)

__global__ __launch_bounds__(BLOCK) void bce_stage1(
    const float* __restrict__ x, const int* __restrict__ gt,
    int n, float* __restrict__ part) {
  float s1 = 0.0f, s0 = 0.0f, cnt = 0.0f;

  const int tid = blockIdx.x * BLOCK + threadIdx.x;
  const int stride = GRID * BLOCK;
  const int n4 = n >> 2;
  const float4* __restrict__ x4 = reinterpret_cast<const float4*>(x);
  const int4* __restrict__ g4 = reinterpret_cast<const int4*>(gt);

  int i = tid;
  // Unrolled x4: issue 8 independent 16B loads before any use (MLP).
  for (; i + 3 * stride < n4; i += 4 * stride) {
    float4 xa = x4[i];
    float4 xb = x4[i + stride];
    float4 xc = x4[i + 2 * stride];
    float4 xd = x4[i + 3 * stride];
    int4 ga = g4[i];
    int4 gb = g4[i + stride];
    int4 gc = g4[i + 2 * stride];
    int4 gd = g4[i + 3 * stride];
    ACC4(xa, ga) ACC4(xb, gb) ACC4(xc, gc) ACC4(xd, gd)
  }
  for (; i < n4; i += stride) {
    float4 xa = x4[i];
    int4 ga = g4[i];
    ACC4(xa, ga)
  }
  // tail elements (n not divisible by 4)
  for (int j = (n4 << 2) + tid; j < n; j += stride) {
    float xe = x[j];
    int ge = gt[j];
    ACC1(xe, ge)
  }

  // wave-level reduction (64 lanes)
  for (int off = 32; off > 0; off >>= 1) {
    s1  += __shfl_down(s1, off, 64);
    s0  += __shfl_down(s0, off, 64);
    cnt += __shfl_down(cnt, off, 64);
  }

  __shared__ float red[3][BLOCK / 64];
  const int lane = threadIdx.x & 63;
  const int wave = threadIdx.x >> 6;
  if (lane == 0) {
    red[0][wave] = s1;
    red[1][wave] = s0;
    red[2][wave] = cnt;
  }
  __syncthreads();
  if (threadIdx.x == 0) {
    float bs1 = red[0][0] + red[0][1] + red[0][2] + red[0][3];
    float bs0 = red[1][0] + red[1][1] + red[1][2] + red[1][3];
    float bc  = red[2][0] + red[2][1] + red[2][2] + red[2][3];
    part[blockIdx.x] = bs1;             // distinct slots: no atomics
    part[GRID + blockIdx.x] = bs0;
    part[2 * GRID + blockIdx.x] = bc;
  }
}

__global__ __launch_bounds__(BLOCK) void bce_stage2(
    const float* __restrict__ part, float* __restrict__ out, double n) {
  double s1 = 0.0, s0 = 0.0, cnt = 0.0;
  for (int i = threadIdx.x; i < GRID; i += BLOCK) {
    s1  += (double)part[i];
    s0  += (double)part[GRID + i];
    cnt += (double)part[2 * GRID + i];
  }
  for (int off = 32; off > 0; off >>= 1) {
    s1  += __shfl_down(s1, off, 64);
    s0  += __shfl_down(s0, off, 64);
    cnt += __shfl_down(cnt, off, 64);
  }
  __shared__ double red[3][BLOCK / 64];
  const int lane = threadIdx.x & 63;
  const int wave = threadIdx.x >> 6;
  if (lane == 0) {
    red[0][wave] = s1;
    red[1][wave] = s0;
    red[2][wave] = cnt;
  }
  __syncthreads();
  if (threadIdx.x == 0) {
    double S1 = red[0][0] + red[0][1] + red[0][2] + red[0][3];
    double S0 = red[1][0] + red[1][1] + red[1][2] + red[1][3];
    double s  = red[2][0] + red[2][1] + red[2][2] + red[2][3];
    // result = S1/(2s) + S0/(2(n-s))
    out[0] = (float)(S1 / (2.0 * s) + S0 / (2.0 * (n - s)));
  }
}

extern "C" void kernel_launch(void* const* d_in, const int* in_sizes, int n_in,
                              void* d_out, int out_size, void* d_ws, size_t ws_size,
                              hipStream_t stream) {
  const float* x = (const float*)d_in[0];
  const int* gt = (const int*)d_in[1];
  float* out = (float*)d_out;
  int n = in_sizes[0];

  float* part = (float*)d_ws;  // 3*GRID floats; every slot written each launch

  bce_stage1<<<GRID, BLOCK, 0, stream>>>(x, gt, n, part);
  bce_stage2<<<1, BLOCK, 0, stream>>>(part, out, (double)n);
}